// Round 2
// baseline (548.036 us; speedup 1.0000x reference)
//
#include <hip/hip_runtime.h>
#include <hip/hip_bf16.h>

typedef __attribute__((ext_vector_type(8))) short short8;
typedef __attribute__((ext_vector_type(4))) float f32x4;

static constexpr int T_TOTAL = 500;
static constexpr int BATCH   = 256;
static constexpr int NIN     = 128;
static constexpr int NH1     = 512;
static constexpr int NH2     = 256;
static constexpr int TC      = 100;   // chunk length
static constexpr int NCHUNK  = 5;

__device__ __forceinline__ unsigned short f2bf(float x) {
    __hip_bfloat16 h = __float2bfloat16(x);
    return *reinterpret_cast<unsigned short*>(&h);
}
__device__ __forceinline__ float bf2f(unsigned short u) {
    __hip_bfloat16 h;
    *reinterpret_cast<unsigned short*>(&h) = u;
    return __bfloat162float(h);
}

__device__ __forceinline__ void gload16(const unsigned short* g, unsigned short* l) {
    __builtin_amdgcn_global_load_lds(
        (const __attribute__((address_space(1))) unsigned int*)(g),
        (__attribute__((address_space(3))) unsigned int*)(l),
        16, 0, 0);
}

// Split f32 weights into 3 exact bf16 components: w = hi + mid + lo (~24 bits)
// Also zeroes the two atomic spike counters each launch.
__global__ __launch_bounds__(256) void prep_weights(
    const float* __restrict__ W1, const float* __restrict__ W2,
    unsigned short* __restrict__ w1s,   // [3][512*128]
    unsigned short* __restrict__ w2s,   // [3][256*512]
    unsigned int* __restrict__ cnt1, unsigned int* __restrict__ cnt2)
{
    int idx = blockIdx.x * 256 + threadIdx.x;
    if (idx == 0) { cnt1[0] = 0u; cnt2[0] = 0u; }
    const int n1 = NH1 * NIN;   // 65536
    const int n2 = NH2 * NH1;   // 131072
    if (idx < n1) {
        float w = W1[idx];
        unsigned short hi = f2bf(w);  float r = w - bf2f(hi);
        unsigned short mi = f2bf(r);  r -= bf2f(mi);
        unsigned short lo = f2bf(r);
        w1s[idx] = hi; w1s[n1 + idx] = mi; w1s[2*n1 + idx] = lo;
    }
    if (idx < n2) {
        float w = W2[idx];
        unsigned short hi = f2bf(w);  float r = w - bf2f(hi);
        unsigned short mi = f2bf(r);  r -= bf2f(mi);
        unsigned short lo = f2bf(r);
        w2s[idx] = hi; w2s[n2 + idx] = mi; w2s[2*n2 + idx] = lo;
    }
}

// spikes f32 (exact 0/1) -> bf16
__global__ __launch_bounds__(256) void prep_spikes(
    const float* __restrict__ sp, unsigned short* __restrict__ spb)
{
    int i = blockIdx.x * 256 + threadIdx.x;     // 4,096,000 threads
    int idx4 = i * 4;
    float4 v = *reinterpret_cast<const float4*>(sp + idx4);
    ushort4 o;
    o.x = f2bf(v.x); o.y = f2bf(v.y); o.z = f2bf(v.z); o.w = f2bf(v.w);
    *reinterpret_cast<ushort4*>(spb + idx4) = o;
}

// C[M,N] = A[M,K](bf16) * (B_hi+B_mid+B_lo)[N,K](bf16, row-major = B^T) + bias
// BM=128 BN=128 BK=32; 256 threads (4 waves in 2x2), wave tile 64x64 (4x4 frags).
// Staging via global_load_lds width=16, linear LDS layout.
__global__ __launch_bounds__(256) void gemm_splits(
    const unsigned short* __restrict__ A,
    const unsigned short* __restrict__ Bs,   // [3][N*K]
    const float* __restrict__ bias,
    float* __restrict__ C,
    int M, int N, int K)
{
    __shared__ __align__(16) unsigned short As[128 * 32];        // 8 KB
    __shared__ __align__(16) unsigned short Bsh[3 * 128 * 32];   // 24 KB

    const int tid  = threadIdx.x;
    const int w    = tid >> 6;
    const int lane = tid & 63;
    const int lr   = lane & 15;
    const int lk   = lane >> 4;
    const int wr   = w >> 1;
    const int wc   = w & 1;

    const int m0 = blockIdx.x * 128;
    const int n0 = blockIdx.y * 128;
    const size_t NK = (size_t)N * K;

    // staging pointer setup: each wave issues 2 A + 6 B gload_lds per K-step
    const unsigned short* gA[2];
    unsigned short* lA[2];
#pragma unroll
    for (int j = 0; j < 2; ++j) {
        int row = w * 32 + j * 16 + (lane >> 2);
        gA[j] = A + (size_t)(m0 + row) * K + (lane & 3) * 8;
        lA[j] = &As[(w * 32 + j * 16) * 32];
    }
    const unsigned short* gB[6];
    unsigned short* lB[6];
#pragma unroll
    for (int j = 0; j < 6; ++j) {
        int i = w * 6 + j;
        int s = i >> 3, blk = i & 7;
        int row = blk * 16 + (lane >> 2);
        gB[j] = Bs + (size_t)s * NK + (size_t)(n0 + row) * K + (lane & 3) * 8;
        lB[j] = &Bsh[s * 4096 + blk * 16 * 32];
    }

    f32x4 acc[4][4];
#pragma unroll
    for (int i = 0; i < 4; ++i)
#pragma unroll
        for (int j = 0; j < 4; ++j) acc[i][j] = (f32x4){0.f, 0.f, 0.f, 0.f};

    for (int k0 = 0; k0 < K; k0 += 32) {
#pragma unroll
        for (int j = 0; j < 2; ++j) gload16(gA[j] + k0, lA[j]);
#pragma unroll
        for (int j = 0; j < 6; ++j) gload16(gB[j] + k0, lB[j]);
        __syncthreads();

        short8 af[4];
#pragma unroll
        for (int rb = 0; rb < 4; ++rb)
            af[rb] = *reinterpret_cast<const short8*>(
                &As[(wr * 64 + rb * 16 + lr) * 32 + lk * 8]);
#pragma unroll
        for (int s = 0; s < 3; ++s) {
#pragma unroll
            for (int cb = 0; cb < 4; ++cb) {
                short8 bf = *reinterpret_cast<const short8*>(
                    &Bsh[s * 4096 + (wc * 64 + cb * 16 + lr) * 32 + lk * 8]);
#pragma unroll
                for (int rb = 0; rb < 4; ++rb)
                    acc[rb][cb] = __builtin_amdgcn_mfma_f32_16x16x32_bf16(
                        af[rb], bf, acc[rb][cb], 0, 0, 0);
            }
        }
        __syncthreads();
    }

    // epilogue: C/D layout col=lane&15, row=(lane>>4)*4+j
#pragma unroll
    for (int cb = 0; cb < 4; ++cb) {
        int col = n0 + wc * 64 + cb * 16 + lr;
        float bv = bias[col];
#pragma unroll
        for (int rb = 0; rb < 4; ++rb) {
            int row = m0 + wr * 64 + rb * 16 + lk * 4;
#pragma unroll
            for (int j = 0; j < 4; ++j)
                C[(size_t)(row + j) * N + col] = acc[rb][cb][j] + bv;
        }
    }
}

// LIF scan layer 1: mem = b*mem + cur - s_prev; s = (mem>1); emit spk bf16.
// Per-thread float spike-sum (for readout) + global integer spike count (atomic).
__global__ __launch_bounds__(256) void scan1(
    const float* __restrict__ cur,            // [TC*131072]
    unsigned short* __restrict__ spk,         // [TC*131072] bf16
    float* __restrict__ mem_c, float* __restrict__ s_c, float* __restrict__ sum_c,
    unsigned int* __restrict__ cnt_g,
    int first)
{
    int tid = blockIdx.x * 256 + threadIdx.x;  // 131072
    float mem = first ? 0.f : mem_c[tid];
    float s   = first ? 0.f : s_c[tid];
    float sum = first ? 0.f : sum_c[tid];
    int cnt = 0;
    const float beta = 0.8187307530779818f;    // exp(-1/5)
    for (int t = 0; t < TC; ++t) {
        size_t off = (size_t)t * 131072 + tid;
        float c = cur[off];
        mem = beta * mem + c - s;
        s = (mem > 1.f) ? 1.f : 0.f;
        sum += s;
        cnt += (mem > 1.f) ? 1 : 0;
        spk[off] = (s > 0.5f) ? (unsigned short)0x3F80 : (unsigned short)0;
    }
    mem_c[tid] = mem; s_c[tid] = s; sum_c[tid] = sum;
    // wave-level integer reduce, one atomic per wave (deterministic: int)
#pragma unroll
    for (int off = 32; off > 0; off >>= 1) cnt += __shfl_down(cnt, off);
    if ((threadIdx.x & 63) == 0) atomicAdd(cnt_g, (unsigned int)cnt);
}

// LIF scan layer 2: accumulate per-neuron mem-sum + global integer spike count
__global__ __launch_bounds__(256) void scan2(
    const float* __restrict__ cur,             // [TC*65536]
    float* __restrict__ mem_c, float* __restrict__ s_c,
    float* __restrict__ msum_c,
    unsigned int* __restrict__ cnt_g,
    int first)
{
    int tid = blockIdx.x * 256 + threadIdx.x;  // 65536
    float mem  = first ? 0.f : mem_c[tid];
    float s    = first ? 0.f : s_c[tid];
    float msum = first ? 0.f : msum_c[tid];
    int cnt = 0;
    const float beta = 0.9048374180359595f;    // exp(-1/10)
    for (int t = 0; t < TC; ++t) {
        float c = cur[(size_t)t * 65536 + tid];
        mem = beta * mem + c - s;
        s = (mem > 1.f) ? 1.f : 0.f;
        msum += mem;
        cnt += (mem > 1.f) ? 1 : 0;
    }
    mem_c[tid] = mem; s_c[tid] = s; msum_c[tid] = msum;
#pragma unroll
    for (int off = 32; off > 0; off >>= 1) cnt += __shfl_down(cnt, off);
    if ((threadIdx.x & 63) == 0) atomicAdd(cnt_g, (unsigned int)cnt);
}

// out[b,o] = (msum[b,:]/T)@Wr[o,:] + br[o] + (s1sum[b,:]/T)@Ws[o,:] + bs[o]
// block 0 thread 0 also writes the two scalar outputs from the int counters.
__global__ __launch_bounds__(256) void readout(
    const float* __restrict__ msum, const float* __restrict__ s1sum,
    const float* __restrict__ Wr, const float* __restrict__ br,
    const float* __restrict__ Ws, const float* __restrict__ bs,
    const unsigned int* __restrict__ cnt1, const unsigned int* __restrict__ cnt2,
    float* __restrict__ out)
{
    __shared__ float r0[256], r1[256];
    int b = blockIdx.x, t = threadIdx.x;
    const float inv_t = 1.0f / 500.0f;
    float m  = msum[b * 256 + t] * inv_t;
    float p0 = m * Wr[t];
    float p1 = m * Wr[256 + t];
    float sa = s1sum[b * 512 + t] * inv_t;
    float sb = s1sum[b * 512 + 256 + t] * inv_t;
    p0 += sa * Ws[t]       + sb * Ws[256 + t];
    p1 += sa * Ws[512 + t] + sb * Ws[768 + t];
    r0[t] = p0; r1[t] = p1;
    __syncthreads();
    for (int st = 128; st > 0; st >>= 1) {
        if (t < st) { r0[t] += r0[t + st]; r1[t] += r1[t + st]; }
        __syncthreads();
    }
    if (t == 0) {
        out[b * 2 + 0] = r0[0] + br[0] + bs[0];
        out[b * 2 + 1] = r1[0] + br[1] + bs[1];
        if (b == 0) {
            out[512] = (float)cnt1[0] * (1.0f / 65536000.0f);
            out[513] = (float)cnt2[0] * (1.0f / 32768000.0f);
        }
    }
}

extern "C" void kernel_launch(void* const* d_in, const int* in_sizes, int n_in,
                              void* d_out, int out_size, void* d_ws, size_t ws_size,
                              hipStream_t stream) {
    const float* spikes = (const float*)d_in[0];
    const float* W1 = (const float*)d_in[1];
    const float* b1 = (const float*)d_in[2];
    const float* W2 = (const float*)d_in[3];
    const float* b2 = (const float*)d_in[4];
    const float* Wr = (const float*)d_in[5];
    const float* br = (const float*)d_in[6];
    const float* Ws = (const float*)d_in[7];
    const float* bs = (const float*)d_in[8];
    float* out = (float*)d_out;

    char* wsb = (char*)d_ws;
    size_t o = 0;
    unsigned short* w1s  = (unsigned short*)(wsb + o); o += (size_t)3 * 65536 * 2;      // 384 KB
    unsigned short* w2s  = (unsigned short*)(wsb + o); o += (size_t)3 * 131072 * 2;     // 768 KB
    unsigned short* sp16 = (unsigned short*)(wsb + o); o += (size_t)16384000 * 2;       // 32.8 MB
    float*          cur1 = (float*)(wsb + o);          o += (size_t)TC * 131072 * 4;    // 52.4 MB
    unsigned short* spk1 = (unsigned short*)(wsb + o); o += (size_t)TC * 131072 * 2;    // 26.2 MB
    float*          cur2 = (float*)(wsb + o);          o += (size_t)TC * 65536 * 4;     // 26.2 MB
    float* mem1  = (float*)(wsb + o); o += 524288;
    float* s1    = (float*)(wsb + o); o += 524288;
    float* s1sum = (float*)(wsb + o); o += 524288;
    float* mem2  = (float*)(wsb + o); o += 262144;
    float* s2    = (float*)(wsb + o); o += 262144;
    float* msum  = (float*)(wsb + o); o += 262144;
    unsigned int* cnt1 = (unsigned int*)(wsb + o); o += 256;
    unsigned int* cnt2 = (unsigned int*)(wsb + o); o += 256;

    prep_weights<<<512, 256, 0, stream>>>(W1, W2, w1s, w2s, cnt1, cnt2);
    prep_spikes<<<16000, 256, 0, stream>>>(spikes, sp16);

    const int MC = TC * BATCH;   // 25600 rows per chunk
    for (int c = 0; c < NCHUNK; ++c) {
        const unsigned short* Ac = sp16 + (size_t)c * MC * NIN;
        gemm_splits<<<dim3(MC / 128, NH1 / 128), 256, 0, stream>>>(
            Ac, w1s, b1, cur1, MC, NH1, NIN);
        scan1<<<512, 256, 0, stream>>>(cur1, spk1, mem1, s1, s1sum, cnt1, c == 0);
        gemm_splits<<<dim3(MC / 128, NH2 / 128), 256, 0, stream>>>(
            spk1, w2s, b2, cur2, MC, NH2, NH1);
        scan2<<<256, 256, 0, stream>>>(cur2, mem2, s2, msum, cnt2, c == 0);
    }

    readout<<<256, 256, 0, stream>>>(msum, s1sum, Wr, br, Ws, bs, cnt1, cnt2, out);
}